// Round 5
// baseline (1247.656 us; speedup 1.0000x reference)
//
#include <hip/hip_runtime.h>
#include <hip/hip_fp16.h>

// Problem constants
#define BATCH 8
#define NPTS 1500         // N
#define DIM 256           // D
#define M1 1501           // NPTS+1 (couplings dim)
#define KH 1536           // padded row stride for fp16 K matrix (24*64 halves)
#define MROWS 24000       // 2*B*N rows through the MLP
#define ITERS 50
#define MU_PT (1.0f / 3000.0f)
#define MU_BIN 0.5f

__device__ __forceinline__ float4 ld4(const float* p){ return *(const float4*)p; }

typedef _Float16 v2h __attribute__((ext_vector_type(2)));
union U16 { uint4 u; __half2 hh[4]; v2h h[4]; };

#if defined(__has_builtin)
#if __has_builtin(__builtin_amdgcn_fdot2)
#define HAVE_FDOT2 1
#endif
#endif

__device__ __forceinline__ float dot2acc(__half2 a, __half2 b, float c) {
#ifdef HAVE_FDOT2
  union { __half2 hh; v2h h; } A, B; A.hh = a; B.hh = b;
  return __builtin_amdgcn_fdot2(A.h, B.h, c, false);
#else
  float2 fa = __half22float2(a), fb = __half22float2(b);
  return c + fa.x * fb.x + fa.y * fb.y;
#endif
}

// ---------------------------------------------------------------------------
// GEMM 1: H1 = relu([quer | pos_end or pos_start] @ W1 + b1)
// M=24000, K=512, N=256.  BM=128, BN=64, BK=16, 256 thr, 8x4 micro-tile.
// ---------------------------------------------------------------------------
__global__ __launch_bounds__(256) void mlp1_kernel(
    const float* __restrict__ quer, const float* __restrict__ pos_end,
    const float* __restrict__ pos_start, const float* __restrict__ W1,
    const float* __restrict__ b1, float* __restrict__ H)
{
  __shared__ float As[16][128];
  __shared__ float Bs[16][64];
  const int t = threadIdx.x;
  const int tm = t & 15, tn = t >> 4;
  const int m0 = blockIdx.x * 128, n0 = blockIdx.y * 64;
  float acc[8][4];
#pragma unroll
  for (int i = 0; i < 8; ++i)
#pragma unroll
    for (int j = 0; j < 4; ++j) acc[i][j] = 0.f;

  for (int kt = 0; kt < 512; kt += 16) {
#pragma unroll
    for (int it = 0; it < 2; ++it) {
      int s = t + it * 256;
      int m = s >> 2, kq = s & 3;
      int row = m0 + m;
      int col = kt + (kq << 2);
      float4 v = make_float4(0.f, 0.f, 0.f, 0.f);
      if (row < MROWS) {
        int r12 = (row < 12000) ? row : row - 12000;
        const float* src;
        if (col < 256) src = quer + (size_t)r12 * 256 + col;
        else src = ((row < 12000) ? pos_end : pos_start) + (size_t)r12 * 256 + (col - 256);
        v = ld4(src);
      }
      int kk = kq << 2;
      As[kk + 0][m] = v.x; As[kk + 1][m] = v.y; As[kk + 2][m] = v.z; As[kk + 3][m] = v.w;
    }
    {
      int kr = t >> 4, nq = t & 15;
      float4 w = ld4(W1 + (size_t)(kt + kr) * 256 + n0 + (nq << 2));
      *(float4*)&Bs[kr][nq << 2] = w;
    }
    __syncthreads();
#pragma unroll
    for (int k = 0; k < 16; ++k) {
      float4 a0 = *(float4*)&As[k][tm << 2];
      float4 a1 = *(float4*)&As[k][64 + (tm << 2)];
      float4 b  = *(float4*)&Bs[k][tn << 2];
      float am[8] = {a0.x, a0.y, a0.z, a0.w, a1.x, a1.y, a1.z, a1.w};
      float bn[4] = {b.x, b.y, b.z, b.w};
#pragma unroll
      for (int i = 0; i < 8; ++i)
#pragma unroll
        for (int j = 0; j < 4; ++j) acc[i][j] += am[i] * bn[j];
    }
    __syncthreads();
  }
  float4 bb = ld4(b1 + n0 + (tn << 2));
  float bn[4] = {bb.x, bb.y, bb.z, bb.w};
#pragma unroll
  for (int i = 0; i < 8; ++i) {
    int row = m0 + ((i < 4) ? ((tm << 2) + i) : (64 + (tm << 2) + i - 4));
    if (row < MROWS) {
      float4 o;
      o.x = fmaxf(acc[i][0] + bn[0], 0.f);
      o.y = fmaxf(acc[i][1] + bn[1], 0.f);
      o.z = fmaxf(acc[i][2] + bn[2], 0.f);
      o.w = fmaxf(acc[i][3] + bn[3], 0.f);
      *(float4*)&H[(size_t)row * 256 + n0 + (tn << 2)] = o;
    }
  }
}

// ---------------------------------------------------------------------------
// GEMM: out = act(A @ W + b), A:[M][256], W:[256][256]
// ---------------------------------------------------------------------------
template<int RELU>
__global__ __launch_bounds__(256) void gemm_bias_kernel(
    const float* __restrict__ A, const float* __restrict__ W,
    const float* __restrict__ bias, float* __restrict__ out, int M)
{
  __shared__ float As[16][128];
  __shared__ float Bs[16][64];
  const int t = threadIdx.x;
  const int tm = t & 15, tn = t >> 4;
  const int m0 = blockIdx.x * 128, n0 = blockIdx.y * 64;
  float acc[8][4];
#pragma unroll
  for (int i = 0; i < 8; ++i)
#pragma unroll
    for (int j = 0; j < 4; ++j) acc[i][j] = 0.f;

  for (int kt = 0; kt < 256; kt += 16) {
#pragma unroll
    for (int it = 0; it < 2; ++it) {
      int s = t + it * 256;
      int m = s >> 2, kq = s & 3;
      int row = m0 + m;
      int col = kt + (kq << 2);
      float4 v = make_float4(0.f, 0.f, 0.f, 0.f);
      if (row < M) v = ld4(A + (size_t)row * 256 + col);
      int kk = kq << 2;
      As[kk + 0][m] = v.x; As[kk + 1][m] = v.y; As[kk + 2][m] = v.z; As[kk + 3][m] = v.w;
    }
    {
      int kr = t >> 4, nq = t & 15;
      float4 w = ld4(W + (size_t)(kt + kr) * 256 + n0 + (nq << 2));
      *(float4*)&Bs[kr][nq << 2] = w;
    }
    __syncthreads();
#pragma unroll
    for (int k = 0; k < 16; ++k) {
      float4 a0 = *(float4*)&As[k][tm << 2];
      float4 a1 = *(float4*)&As[k][64 + (tm << 2)];
      float4 b  = *(float4*)&Bs[k][tn << 2];
      float am[8] = {a0.x, a0.y, a0.z, a0.w, a1.x, a1.y, a1.z, a1.w};
      float bn[4] = {b.x, b.y, b.z, b.w};
#pragma unroll
      for (int i = 0; i < 8; ++i)
#pragma unroll
        for (int j = 0; j < 4; ++j) acc[i][j] += am[i] * bn[j];
    }
    __syncthreads();
  }
  float4 bb = ld4(bias + n0 + (tn << 2));
  float bn[4] = {bb.x, bb.y, bb.z, bb.w};
#pragma unroll
  for (int i = 0; i < 8; ++i) {
    int row = m0 + ((i < 4) ? ((tm << 2) + i) : (64 + (tm << 2) + i - 4));
    if (row < M) {
      float4 o;
      o.x = acc[i][0] + bn[0]; o.y = acc[i][1] + bn[1];
      o.z = acc[i][2] + bn[2]; o.w = acc[i][3] + bn[3];
      if (RELU) { o.x = fmaxf(o.x, 0.f); o.y = fmaxf(o.y, 0.f); o.z = fmaxf(o.z, 0.f); o.w = fmaxf(o.w, 0.f); }
      *(float4*)&out[(size_t)row * 256 + n0 + (tn << 2)] = o;
    }
  }
}

// ---------------------------------------------------------------------------
// Scores: Kh[b][i][j] = fp16(exp(f1_i . f2_j / 16)), diag->0, pads->0.
// ---------------------------------------------------------------------------
__global__ __launch_bounds__(256) void scores_kernel(
    const float* __restrict__ F, __half* __restrict__ Kh)
{
  __shared__ float As[16][128];
  __shared__ float Bs[16][64];
  const int t = threadIdx.x;
  const int tm = t & 15, tn = t >> 4;
  const int b = blockIdx.z;
  const int m0 = blockIdx.x * 128, n0 = blockIdx.y * 64;
  const float* F1 = F + (size_t)b * NPTS * 256;
  const float* F2 = F + (size_t)(12000 + b * NPTS) * 256;
  __half* Kb = Kh + (size_t)b * M1 * KH;
  float acc[8][4];
#pragma unroll
  for (int i = 0; i < 8; ++i)
#pragma unroll
    for (int j = 0; j < 4; ++j) acc[i][j] = 0.f;

  for (int kt = 0; kt < 256; kt += 16) {
#pragma unroll
    for (int it = 0; it < 2; ++it) {
      int s = t + it * 256;
      int m = s >> 2, kq = s & 3;
      int row = m0 + m;
      float4 v = make_float4(0.f, 0.f, 0.f, 0.f);
      if (row < NPTS) v = ld4(F1 + (size_t)row * 256 + kt + (kq << 2));
      int kk = kq << 2;
      As[kk + 0][m] = v.x; As[kk + 1][m] = v.y; As[kk + 2][m] = v.z; As[kk + 3][m] = v.w;
    }
    {
      int n = t >> 2, kq = t & 3;
      float4 v = make_float4(0.f, 0.f, 0.f, 0.f);
      if (n0 + n < NPTS) v = ld4(F2 + (size_t)(n0 + n) * 256 + kt + (kq << 2));
      int kk = kq << 2;
      Bs[kk + 0][n] = v.x; Bs[kk + 1][n] = v.y; Bs[kk + 2][n] = v.z; Bs[kk + 3][n] = v.w;
    }
    __syncthreads();
#pragma unroll
    for (int k = 0; k < 16; ++k) {
      float4 a0 = *(float4*)&As[k][tm << 2];
      float4 a1 = *(float4*)&As[k][64 + (tm << 2)];
      float4 b4 = *(float4*)&Bs[k][tn << 2];
      float am[8] = {a0.x, a0.y, a0.z, a0.w, a1.x, a1.y, a1.z, a1.w};
      float bn[4] = {b4.x, b4.y, b4.z, b4.w};
#pragma unroll
      for (int i = 0; i < 8; ++i)
#pragma unroll
        for (int j = 0; j < 4; ++j) acc[i][j] += am[i] * bn[j];
    }
    __syncthreads();
  }
#pragma unroll
  for (int i = 0; i < 8; ++i) {
    int gi = m0 + ((i < 4) ? ((tm << 2) + i) : (64 + (tm << 2) + i - 4));
    if (gi < NPTS) {
      int gj0 = n0 + (tn << 2);
      float v[4];
#pragma unroll
      for (int j = 0; j < 4; ++j) {
        int gj = gj0 + j;
        v[j] = (gj < NPTS && gj != gi) ? expf(acc[i][j] * 0.0625f) : 0.f;
      }
      __half2 h0 = __floats2half2_rn(v[0], v[1]);
      __half2 h1 = __floats2half2_rn(v[2], v[3]);
      union { __half2 h[2]; uint2 u; } U; U.h[0] = h0; U.h[1] = h1;
      *(uint2*)&Kb[(size_t)gi * KH + gj0] = U.u;   // 8B aligned store
    }
  }
}

// ---------------------------------------------------------------------------
// bins: bin row/col = fp16(exp(alpha)); zero bin-row pads; zero csum0.
// ---------------------------------------------------------------------------
__global__ void bins_kernel(__half* __restrict__ Kh, const float* __restrict__ palpha,
                            float* __restrict__ csum0)
{
  int gid = blockIdx.x * 256 + threadIdx.x;
  if (gid >= BATCH * KH) return;
  int b = gid / KH, x = gid % KH;
  __half He = __float2half(expf(palpha[0]));
  __half* Kb = Kh + (size_t)b * M1 * KH;
  csum0[gid] = 0.f;
  if (x < M1) {
    Kb[(size_t)NPTS * KH + x] = He;   // bin row
    Kb[(size_t)x * KH + NPTS] = He;   // bin col (corner included)
  } else {
    Kb[(size_t)NPTS * KH + x] = __float2half(0.f); // bin-row pads
  }
}

// ---------------------------------------------------------------------------
// Fused Sinkhorn iteration (fp16 K), ONE dispatch per iteration.
// Grid 1280 = 160 blocks/batch (bb = blockIdx%8 for XCD affinity), 640
// waves/batch; wave wv handles rows i = wv, wv+640, ... (<=3 rows).
//  A) ev into LDS as fp16 (3 KB); block rb==0 zeros csum_zero.
//  B) per row: 3x16B loads (prefetched one row ahead), dot via v_dot2
//     (fp32 acc), shuffle-reduce, eu_i = mu/dot; col partials via hfma2.
//  C) unpack fp16 partials -> fp32, 4-wave LDS combine, atomicAdd csum_cur.
// LDS 27.6 KB -> 5 blocks/CU; grid 1280 fully resident (20 waves/CU).
// ---------------------------------------------------------------------------
__global__ __launch_bounds__(256) void sink_iter_kernel(
    const __half* __restrict__ Kh,
    const float* __restrict__ csum_prev,
    float* __restrict__ csum_cur,
    float* __restrict__ csum_zero,
    float* __restrict__ eu, int first)
{
  const int t = threadIdx.x;
  const int wave = t >> 6, lane = t & 63;
  const int bb = blockIdx.x & 7;   // batch == XCD (heuristic)
  const int rb = blockIdx.x >> 3;  // block-in-batch, 0..159
  const int wv = (rb << 2) | wave; // wave-in-batch, 0..639
  const int STEP = 640;
  const __half* Kb = Kh + (size_t)bb * M1 * KH;
  float* eub = eu + bb * KH;

  __shared__ __align__(16) __half evsh[KH];
  __shared__ __align__(16) float wpart[4][KH];

  if (rb == 0) {
    for (int j = t; j < KH; j += 256) csum_zero[bb * KH + j] = 0.f;
  }
  // phase A: ev into LDS (fp16)
  if (first) {
    for (int j = t; j < KH; j += 256) evsh[j] = __float2half(j < M1 ? 1.f : 0.f);
  } else {
    for (int j = t; j < KH; j += 256) {
      float nu = (j < NPTS) ? MU_PT : ((j == NPTS) ? MU_BIN : 0.f);
      float e = (j < M1) ? (nu / csum_prev[bb * KH + j]) : 0.f;
      evsh[j] = __float2half(e);
    }
  }
  __syncthreads();

  // phase B: rows, with one-row-ahead prefetch
  __half2 acc2[12];
#pragma unroll
  for (int k = 0; k < 12; ++k) acc2[k] = __floats2half2_rn(0.f, 0.f);

  int i = wv;
  U16 cur[3];
  if (i < M1) {
#pragma unroll
    for (int k = 0; k < 3; ++k)
      cur[k].u = *(const uint4*)(Kb + (size_t)i * KH + ((size_t)(lane + (k << 6)) << 3));
  }
  while (i < M1) {
    int inx = i + STEP;
    U16 nxt[3];
    if (inx < M1) {
#pragma unroll
      for (int k = 0; k < 3; ++k)
        nxt[k].u = *(const uint4*)(Kb + (size_t)inx * KH + ((size_t)(lane + (k << 6)) << 3));
    }
    // dot(K_row, ev) using packed fp16 dot with fp32 accumulator
    float d0 = 0.f, d1 = 0.f;
#pragma unroll
    for (int k = 0; k < 3; ++k) {
      int c = lane + (k << 6);
      U16 E; E.u = *(const uint4*)&evsh[c << 3];   // 8 halves of ev
      d0 = dot2acc(cur[k].hh[0], E.hh[0], d0);
      d1 = dot2acc(cur[k].hh[1], E.hh[1], d1);
      d0 = dot2acc(cur[k].hh[2], E.hh[2], d0);
      d1 = dot2acc(cur[k].hh[3], E.hh[3], d1);
    }
    float dot = d0 + d1;
#pragma unroll
    for (int off = 32; off > 0; off >>= 1) dot += __shfl_xor(dot, off);
    float mu = (i < NPTS) ? MU_PT : MU_BIN;
    float euv = mu / dot;
    if (lane == 0) eub[i] = euv;
    __half2 e2 = __float2half2_rn(euv);
#pragma unroll
    for (int k = 0; k < 3; ++k)
#pragma unroll
      for (int m = 0; m < 4; ++m)
        acc2[k * 4 + m] = __hfma2(cur[k].hh[m], e2, acc2[k * 4 + m]);
#pragma unroll
    for (int k = 0; k < 3; ++k) cur[k] = nxt[k];
    i = inx;
  }

  // phase C: unpack fp16 partials -> fp32 wpart, combine 4 waves, atomics
#pragma unroll
  for (int k = 0; k < 3; ++k) {
    int c = lane + (k << 6);
    float2 f0 = __half22float2(acc2[k * 4 + 0]);
    float2 f1 = __half22float2(acc2[k * 4 + 1]);
    float2 f2 = __half22float2(acc2[k * 4 + 2]);
    float2 f3 = __half22float2(acc2[k * 4 + 3]);
    *(float4*)&wpart[wave][(c << 3)]     = make_float4(f0.x, f0.y, f1.x, f1.y);
    *(float4*)&wpart[wave][(c << 3) + 4] = make_float4(f2.x, f2.y, f3.x, f3.y);
  }
  __syncthreads();
  for (int j = t; j < M1; j += 256) {
    float s = wpart[0][j] + wpart[1][j] + wpart[2][j] + wpart[3][j];
    atomicAdd(&csum_cur[bb * KH + j], s);
  }
}

// Final ev from last iteration's csum
__global__ void final_ev_kernel(const float* __restrict__ csum,
                                float* __restrict__ ev)
{
  int j = blockIdx.x * 256 + threadIdx.x;
  int bb = blockIdx.y;
  if (j >= M1) return;
  float nu = (j < NPTS) ? MU_PT : MU_BIN;
  ev[bb * KH + j] = nu / csum[bb * KH + j];
}

// out[b][i][j] = Kh * eu_i * ev_j * 3000 ; one block per output row
__global__ __launch_bounds__(256) void finalize_kernel(
    const __half* __restrict__ Kh, const float* __restrict__ eu,
    const float* __restrict__ ev, float* __restrict__ out)
{
  int rowid = blockIdx.x;                 // 0 .. BATCH*M1-1
  int b = rowid / M1, i = rowid % M1;
  const __half* krow = Kh + ((size_t)b * M1 + i) * KH;
  const float* evb = ev + b * KH;
  float* orow = out + (size_t)rowid * M1;
  float scale = eu[b * KH + i] * 3000.0f;
  for (int j = threadIdx.x; j < M1; j += 256)
    orow[j] = __half2float(krow[j]) * evb[j] * scale;
}

// ---------------------------------------------------------------------------
extern "C" void kernel_launch(void* const* d_in, const int* in_sizes, int n_in,
                              void* d_out, int out_size, void* d_ws, size_t ws_size,
                              hipStream_t stream)
{
  const float* quer      = (const float*)d_in[0];
  const float* pos_start = (const float*)d_in[1];
  const float* pos_end   = (const float*)d_in[2];
  const float* W1 = (const float*)d_in[3];
  const float* b1 = (const float*)d_in[4];
  const float* W2 = (const float*)d_in[5];
  const float* b2 = (const float*)d_in[6];
  const float* W3 = (const float*)d_in[7];
  const float* b3 = (const float*)d_in[8];
  const float* alpha = (const float*)d_in[9];

  char* ws = (char*)d_ws;
  size_t off = 0;
  auto carve = [&](size_t bytes) -> void* {
    void* p = ws + off;
    off += (bytes + 1023) & ~(size_t)1023;
    return p;
  };
  float*  H1 = (float*)carve((size_t)MROWS * 256 * 4);            // 24.6 MB
  float*  H2 = (float*)carve((size_t)MROWS * 256 * 4);            // 24.6 MB
  __half* Kh = (__half*)carve((size_t)BATCH * M1 * KH * 2);       // 36.9 MB
  float* csum[3];
  for (int c = 0; c < 3; ++c) csum[c] = (float*)carve((size_t)BATCH * KH * 4);
  float* eu = (float*)carve((size_t)BATCH * KH * 4);
  float* ev = (float*)carve((size_t)BATCH * KH * 4);
  (void)ws_size; (void)in_sizes; (void)n_in; (void)out_size;

  dim3 blk(256);
  // MLP: f1 rows [0,12000) use pos_end; f2 rows [12000,24000) use pos_start
  mlp1_kernel<<<dim3(188, 4), blk, 0, stream>>>(quer, pos_end, pos_start, W1, b1, H1);
  gemm_bias_kernel<1><<<dim3(188, 4), blk, 0, stream>>>(H1, W2, b2, H2, MROWS);
  gemm_bias_kernel<0><<<dim3(188, 4), blk, 0, stream>>>(H2, W3, b3, H1, MROWS);
  // scores -> Kh (fp16 exp domain, pads zeroed), bins + csum[0] zero
  scores_kernel<<<dim3(12, 24, 8), blk, 0, stream>>>(H1, Kh);
  bins_kernel<<<dim3((BATCH * KH + 255) / 256), blk, 0, stream>>>(Kh, alpha, csum[0]);
  // sinkhorn: 50 fused dispatches, triple-buffered csum
  for (int it = 0; it < ITERS; ++it) {
    float* prev = csum[(it + 2) % 3];
    float* cur  = csum[it % 3];
    float* znxt = csum[(it + 1) % 3];
    sink_iter_kernel<<<dim3(1280), blk, 0, stream>>>(Kh, prev, cur, znxt, eu, it == 0 ? 1 : 0);
  }
  final_ev_kernel<<<dim3(6, 8), blk, 0, stream>>>(csum[(ITERS - 1) % 3], ev);
  // output
  finalize_kernel<<<dim3(BATCH * M1), blk, 0, stream>>>(Kh, eu, ev, (float*)d_out);
}

// Round 6
// 786.865 us; speedup vs baseline: 1.5856x; 1.5856x over previous
//
#include <hip/hip_runtime.h>
#include <hip/hip_fp16.h>

// Problem constants
#define BATCH 8
#define NPTS 1500         // N
#define DIM 256           // D
#define M1 1501           // NPTS+1 (couplings dim)
#define KH 1536           // padded row stride for fp16 K matrix (24*64 halves)
#define MROWS 24000       // 2*B*N rows through the MLP
#define ITERS 50
#define MU_PT (1.0f / 3000.0f)
#define MU_BIN 0.5f

typedef _Float16 half8 __attribute__((ext_vector_type(8)));
typedef float f32x4 __attribute__((ext_vector_type(4)));

__device__ __forceinline__ float4 ld4(const float* p){ return *(const float4*)p; }

// ---------------------------------------------------------------------------
// prep: Wt[n][k] = fp16(W[k][n]) for W1 (512x256), W2, W3 (256x256).
// One-time, ~0.26M elements.
// ---------------------------------------------------------------------------
__global__ void prep_w_kernel(const float* __restrict__ W1, const float* __restrict__ W2,
                              const float* __restrict__ W3, __half* __restrict__ Wt1,
                              __half* __restrict__ Wt2, __half* __restrict__ Wt3)
{
  int gid = blockIdx.x * 256 + threadIdx.x;
  if (gid < 512 * 256) {
    int n = gid >> 9, k = gid & 511;
    Wt1[gid] = __float2half(W1[k * 256 + n]);
  } else if (gid < 512 * 256 + 256 * 256) {
    int g = gid - 512 * 256; int n = g >> 8, k = g & 255;
    Wt2[g] = __float2half(W2[k * 256 + n]);
  } else if (gid < 512 * 256 + 2 * 256 * 256) {
    int g = gid - 512 * 256 - 256 * 256; int n = g >> 8, k = g & 255;
    Wt3[g] = __float2half(W3[k * 256 + n]);
  }
}

// ---------------------------------------------------------------------------
// MFMA fp16 GEMM, 128x128x32 tiles, 4 waves x (4x4 of 16x16x32 MFMA).
// MODE 0: A = [quer|pos] fp32 (convert in staging), B = Wt1[n][512], relu -> H fp16
// MODE 1: A = H fp16,  B = Wt[n][256], relu -> H fp16
// MODE 2: A = H fp16,  B = Wt[n][256], linear -> H fp16
// MODE 3: scores: A = F1 rows, B = F2 rows ([n][k] natively), out Kh fp16:
//         Kh[gi][gj] = (gj<NPTS && gj!=gi) ? exp(acc/16) : 0   (pads zeroed)
// Fragment layouts (m89/m120-verified): A[m=lane&15][k=quad*8+j],
// B[k=quad*8+j][n=lane&15], D[row=quad*4+reg][col=lane&15].
// LDS stride 40 halves -> 2-way bank aliasing (free).
// ---------------------------------------------------------------------------
template<int MODE>
__global__ __launch_bounds__(256) void mfma_gemm_kernel(
    const float* __restrict__ Aq, const float* __restrict__ Ap_end,
    const float* __restrict__ Ap_start, const __half* __restrict__ Ah,
    const __half* __restrict__ Bh, const float* __restrict__ bias,
    __half* __restrict__ out)
{
  const int K = (MODE == 0) ? 512 : 256;
  const int M = (MODE == 3) ? NPTS : MROWS;
  __shared__ _Float16 As[128][40];
  __shared__ _Float16 Bs[128][40];
  const int t = threadIdx.x;
  const int lane = t & 63;
  const int wave = t >> 6;
  const int quad = lane >> 4, l15 = lane & 15;
  const int wm = wave & 1, wn = wave >> 1;
  const int m0 = blockIdx.x * 128;
  const int n0 = blockIdx.y * 128;
  const int b  = (MODE == 3) ? blockIdx.z : 0;
  const __half* F1 = Ah + (size_t)b * NPTS * 256;
  const __half* F2 = Ah + (size_t)(12000 + b * NPTS) * 256;

  f32x4 acc[4][4];
#pragma unroll
  for (int i = 0; i < 4; ++i)
#pragma unroll
    for (int j = 0; j < 4; ++j) acc[i][j] = (f32x4){0.f, 0.f, 0.f, 0.f};

  const int sr = t >> 1;            // staging row 0..127
  const int c0 = (t & 1) * 16;      // staging col offset {0,16}

  for (int kt = 0; kt < K; kt += 32) {
    // ---- stage A tile (128 x 32 halves) ----
    {
      int grow = m0 + sr;
      if (MODE == 0) {
        union { half8 v[2]; _Float16 s[16]; } U;
        if (grow < M) {
          int col = kt + c0;
          int r12 = (grow < 12000) ? grow : grow - 12000;
          const float* src;
          if (col < 256) src = Aq + (size_t)r12 * 256 + col;
          else src = ((grow < 12000) ? Ap_end : Ap_start) + (size_t)r12 * 256 + (col - 256);
#pragma unroll
          for (int i = 0; i < 4; ++i) {
            float4 w = ld4(src + 4 * i);
            U.s[4*i+0] = (_Float16)w.x; U.s[4*i+1] = (_Float16)w.y;
            U.s[4*i+2] = (_Float16)w.z; U.s[4*i+3] = (_Float16)w.w;
          }
        } else {
#pragma unroll
          for (int i = 0; i < 16; ++i) U.s[i] = (_Float16)0.f;
        }
        *(half8*)&As[sr][c0]     = U.v[0];
        *(half8*)&As[sr][c0 + 8] = U.v[1];
      } else {
        const __half* src = ((MODE == 3) ? F1 : Ah) + (size_t)grow * 256 + kt + c0;
        uint4 u0 = make_uint4(0,0,0,0), u1 = make_uint4(0,0,0,0);
        if (grow < M) { u0 = *(const uint4*)src; u1 = *(const uint4*)(src + 8); }
        *(uint4*)&As[sr][c0]     = u0;
        *(uint4*)&As[sr][c0 + 8] = u1;
      }
    }
    // ---- stage B tile (128 n-rows x 32 k) ----
    {
      int n = n0 + sr;
      uint4 u0 = make_uint4(0,0,0,0), u1 = make_uint4(0,0,0,0);
      if (MODE == 3) {
        if (n < NPTS) {
          const __half* src = F2 + (size_t)n * 256 + kt + c0;
          u0 = *(const uint4*)src; u1 = *(const uint4*)(src + 8);
        }
      } else {
        const __half* src = Bh + (size_t)n * K + kt + c0;
        u0 = *(const uint4*)src; u1 = *(const uint4*)(src + 8);
      }
      *(uint4*)&Bs[sr][c0]     = u0;
      *(uint4*)&Bs[sr][c0 + 8] = u1;
    }
    __syncthreads();
    // ---- MFMA ----
    half8 af[4], bf[4];
#pragma unroll
    for (int sm = 0; sm < 4; ++sm)
      af[sm] = *(half8*)&As[wm * 64 + sm * 16 + l15][quad * 8];
#pragma unroll
    for (int sn = 0; sn < 4; ++sn)
      bf[sn] = *(half8*)&Bs[wn * 64 + sn * 16 + l15][quad * 8];
#pragma unroll
    for (int sm = 0; sm < 4; ++sm)
#pragma unroll
      for (int sn = 0; sn < 4; ++sn)
        acc[sm][sn] = __builtin_amdgcn_mfma_f32_16x16x32_f16(af[sm], bf[sn], acc[sm][sn], 0, 0, 0);
    __syncthreads();
  }

  // ---- epilogue ----
  if (MODE == 3) {
    __half* Kb = out + (size_t)b * M1 * KH;
#pragma unroll
    for (int sm = 0; sm < 4; ++sm) {
      int rbase = m0 + wm * 64 + sm * 16 + quad * 4;
#pragma unroll
      for (int reg = 0; reg < 4; ++reg) {
        int gi = rbase + reg;
        if (gi < NPTS) {
#pragma unroll
          for (int sn = 0; sn < 4; ++sn) {
            int gj = n0 + wn * 64 + sn * 16 + l15;
            float v = acc[sm][sn][reg] * 0.0625f;
            float kv = (gj < NPTS && gj != gi) ? __expf(v) : 0.f;
            Kb[(size_t)gi * KH + gj] = __float2half(kv);
          }
        }
      }
    }
  } else {
    float bv[4];
#pragma unroll
    for (int sn = 0; sn < 4; ++sn) bv[sn] = bias[n0 + wn * 64 + sn * 16 + l15];
#pragma unroll
    for (int sm = 0; sm < 4; ++sm) {
      int rbase = m0 + wm * 64 + sm * 16 + quad * 4;
#pragma unroll
      for (int reg = 0; reg < 4; ++reg) {
        int gr = rbase + reg;
        if (gr < MROWS) {
#pragma unroll
          for (int sn = 0; sn < 4; ++sn) {
            int col = n0 + wn * 64 + sn * 16 + l15;
            float v = acc[sm][sn][reg] + bv[sn];
            if (MODE != 2) v = fmaxf(v, 0.f);
            out[(size_t)gr * 256 + col] = __float2half(v);
          }
        }
      }
    }
  }
}

// ---------------------------------------------------------------------------
// bins: bin row/col = fp16(exp(alpha)); zero bin-row pads; zero csum0.
// ---------------------------------------------------------------------------
__global__ void bins_kernel(__half* __restrict__ Kh, const float* __restrict__ palpha,
                            float* __restrict__ csum0)
{
  int gid = blockIdx.x * 256 + threadIdx.x;
  if (gid >= BATCH * KH) return;
  int b = gid / KH, x = gid % KH;
  __half He = __float2half(expf(palpha[0]));
  __half* Kb = Kh + (size_t)b * M1 * KH;
  csum0[gid] = 0.f;
  if (x < M1) {
    Kb[(size_t)NPTS * KH + x] = He;   // bin row
    Kb[(size_t)x * KH + NPTS] = He;   // bin col (corner included)
  } else {
    Kb[(size_t)NPTS * KH + x] = __float2half(0.f); // bin-row pads
  }
}

// ---------------------------------------------------------------------------
// Fused Sinkhorn iteration (fp16 K), ONE dispatch per iteration.
// (round-4 verified version: fp32 accumulation path, grid 512 = 64 blk/batch)
// ---------------------------------------------------------------------------
__global__ __launch_bounds__(256) void sink_iter_kernel(
    const __half* __restrict__ Kh,
    const float* __restrict__ csum_prev,
    float* __restrict__ csum_cur,
    float* __restrict__ csum_zero,
    float* __restrict__ eu, int first)
{
  const int t = threadIdx.x;
  const int wave = t >> 6, lane = t & 63;
  const int bb = blockIdx.x & 7;   // batch == XCD (heuristic)
  const int rb = blockIdx.x >> 3;  // block-in-batch, 0..63
  const int wv = (rb << 2) | wave; // wave-in-batch, 0..255
  const __half* Kb = Kh + (size_t)bb * M1 * KH;
  float* eub = eu + bb * KH;

  __shared__ __align__(16) float evs[KH];
  __shared__ __align__(16) float wpart[4][KH];

  if (rb == 0) {
    for (int j = t; j < KH; j += 256) csum_zero[bb * KH + j] = 0.f;
  }
  // phase A: ev into LDS
  if (first) {
    for (int j = t; j < KH; j += 256) evs[j] = (j < M1) ? 1.0f : 0.f;
  } else {
    for (int j = t; j < KH; j += 256) {
      float nu = (j < NPTS) ? MU_PT : ((j == NPTS) ? MU_BIN : 0.f);
      evs[j] = (j < M1) ? (nu / csum_prev[bb * KH + j]) : 0.f;
    }
  }
  __syncthreads();

  // phase B: rows
  float acc[24];
#pragma unroll
  for (int k = 0; k < 24; ++k) acc[k] = 0.f;

  for (int i = wv; i < M1; i += 256) {
    const __half* row = Kb + (size_t)i * KH;
    float r[24];
    float dot = 0.f;
#pragma unroll
    for (int k = 0; k < 3; ++k) {
      int c = lane + (k << 6);                 // chunk of 8 halves
      union { uint4 u; __half2 h[4]; } U;
      U.u = *(const uint4*)(row + (c << 3));   // 16B load
#pragma unroll
      for (int m = 0; m < 4; ++m) {
        float2 f = __half22float2(U.h[m]);
        r[k * 8 + 2 * m]     = f.x;
        r[k * 8 + 2 * m + 1] = f.y;
      }
      float4 e0 = *(const float4*)&evs[(c << 3)];
      float4 e1 = *(const float4*)&evs[(c << 3) + 4];
      dot += r[k*8+0]*e0.x + r[k*8+1]*e0.y + r[k*8+2]*e0.z + r[k*8+3]*e0.w
           + r[k*8+4]*e1.x + r[k*8+5]*e1.y + r[k*8+6]*e1.z + r[k*8+7]*e1.w;
    }
#pragma unroll
    for (int off = 32; off > 0; off >>= 1) dot += __shfl_xor(dot, off);
    float mu = (i < NPTS) ? MU_PT : MU_BIN;
    float euv = mu / dot;
    if (lane == 0) eub[i] = euv;
#pragma unroll
    for (int k = 0; k < 24; ++k) acc[k] += r[k] * euv;
  }

  // phase C: combine 4 waves in LDS, atomics into csum_cur
#pragma unroll
  for (int k = 0; k < 3; ++k) {
    int c = lane + (k << 6);
    float4 a0 = make_float4(acc[k*8+0], acc[k*8+1], acc[k*8+2], acc[k*8+3]);
    float4 a1 = make_float4(acc[k*8+4], acc[k*8+5], acc[k*8+6], acc[k*8+7]);
    *(float4*)&wpart[wave][(c << 3)]     = a0;
    *(float4*)&wpart[wave][(c << 3) + 4] = a1;
  }
  __syncthreads();
  for (int j = t; j < M1; j += 256) {
    float s = wpart[0][j] + wpart[1][j] + wpart[2][j] + wpart[3][j];
    atomicAdd(&csum_cur[bb * KH + j], s);
  }
}

// Final ev from last iteration's csum
__global__ void final_ev_kernel(const float* __restrict__ csum,
                                float* __restrict__ ev)
{
  int j = blockIdx.x * 256 + threadIdx.x;
  int bb = blockIdx.y;
  if (j >= M1) return;
  float nu = (j < NPTS) ? MU_PT : MU_BIN;
  ev[bb * KH + j] = nu / csum[bb * KH + j];
}

// out[b][i][j] = Kh * eu_i * ev_j * 3000 ; one block per output row
__global__ __launch_bounds__(256) void finalize_kernel(
    const __half* __restrict__ Kh, const float* __restrict__ eu,
    const float* __restrict__ ev, float* __restrict__ out)
{
  int rowid = blockIdx.x;                 // 0 .. BATCH*M1-1
  int b = rowid / M1, i = rowid % M1;
  const __half* krow = Kh + ((size_t)b * M1 + i) * KH;
  const float* evb = ev + b * KH;
  float* orow = out + (size_t)rowid * M1;
  float scale = eu[b * KH + i] * 3000.0f;
  for (int j = threadIdx.x; j < M1; j += 256)
    orow[j] = __half2float(krow[j]) * evb[j] * scale;
}

// ---------------------------------------------------------------------------
extern "C" void kernel_launch(void* const* d_in, const int* in_sizes, int n_in,
                              void* d_out, int out_size, void* d_ws, size_t ws_size,
                              hipStream_t stream)
{
  const float* quer      = (const float*)d_in[0];
  const float* pos_start = (const float*)d_in[1];
  const float* pos_end   = (const float*)d_in[2];
  const float* W1 = (const float*)d_in[3];
  const float* b1 = (const float*)d_in[4];
  const float* W2 = (const float*)d_in[5];
  const float* b2 = (const float*)d_in[6];
  const float* W3 = (const float*)d_in[7];
  const float* b3 = (const float*)d_in[8];
  const float* alpha = (const float*)d_in[9];

  char* ws = (char*)d_ws;
  size_t off = 0;
  auto carve = [&](size_t bytes) -> void* {
    void* p = ws + off;
    off += (bytes + 1023) & ~(size_t)1023;
    return p;
  };
  __half* Ha  = (__half*)carve((size_t)MROWS * 256 * 2);          // 12.3 MB
  __half* Hb  = (__half*)carve((size_t)MROWS * 256 * 2);          // 12.3 MB
  __half* Kh  = (__half*)carve((size_t)BATCH * M1 * KH * 2);      // 36.9 MB
  __half* Wt1 = (__half*)carve((size_t)256 * 512 * 2);
  __half* Wt2 = (__half*)carve((size_t)256 * 256 * 2);
  __half* Wt3 = (__half*)carve((size_t)256 * 256 * 2);
  float* csum[3];
  for (int c = 0; c < 3; ++c) csum[c] = (float*)carve((size_t)BATCH * KH * 4);
  float* eu = (float*)carve((size_t)BATCH * KH * 4);
  float* ev = (float*)carve((size_t)BATCH * KH * 4);
  (void)ws_size; (void)in_sizes; (void)n_in; (void)out_size;

  dim3 blk(256);
  // weight prep (fp16, transposed to [n][k])
  prep_w_kernel<<<dim3(1024), blk, 0, stream>>>(W1, W2, W3, Wt1, Wt2, Wt3);
  // MLP via MFMA: Ha = relu([q|p]W1+b1); Hb = relu(Ha W2+b2); Ha = Hb W3+b3
  mfma_gemm_kernel<0><<<dim3(188, 2), blk, 0, stream>>>(quer, pos_end, pos_start, nullptr, Wt1, b1, Ha);
  mfma_gemm_kernel<1><<<dim3(188, 2), blk, 0, stream>>>(nullptr, nullptr, nullptr, Ha, Wt2, b2, Hb);
  mfma_gemm_kernel<2><<<dim3(188, 2), blk, 0, stream>>>(nullptr, nullptr, nullptr, Hb, Wt3, b3, Ha);
  // scores -> Kh (fp16 exp domain, pads zeroed)
  mfma_gemm_kernel<3><<<dim3(12, 12, 8), blk, 0, stream>>>(nullptr, nullptr, nullptr, Ha, nullptr, nullptr, Kh);
  bins_kernel<<<dim3((BATCH * KH + 255) / 256), blk, 0, stream>>>(Kh, alpha, csum[0]);
  // sinkhorn: 50 fused dispatches, triple-buffered csum (round-4 kernel)
  for (int it = 0; it < ITERS; ++it) {
    float* prev = csum[(it + 2) % 3];
    float* cur  = csum[it % 3];
    float* znxt = csum[(it + 1) % 3];
    sink_iter_kernel<<<dim3(512), blk, 0, stream>>>(Kh, prev, cur, znxt, eu, it == 0 ? 1 : 0);
  }
  final_ev_kernel<<<dim3(6, 8), blk, 0, stream>>>(csum[(ITERS - 1) % 3], ev);
  // output
  finalize_kernel<<<dim3(BATCH * M1), blk, 0, stream>>>(Kh, eu, ev, (float*)d_out);
}